// Round 1
// baseline (2932.581 us; speedup 1.0000x reference)
//
#include <hip/hip_runtime.h>

// EfficientAttention on MI355X — fp32 baseline, 4-kernel pipeline.
// Shapes: N=2, C=96, Nvox=131072 (32*64*64), HEADS=4, hk=hv=24.
//
// Pipeline:
//  K1 k_proj_kq : read x; compute keys->exp(keys) (+atomic ksum), queries->head-softmax.
//                 writes expk[2,96,NV], qsm[2,96,NV] to ws.
//  K2 k_ctx     : read x (recompute V) + expk; accumulate unnormalized
//                 context[n,kg,v] = sum_p expk[kg,p]*v[v,p] via atomics.
//  K3 k_combine : M[n][o][kg] = sum_v Wr[o, h*24+v] * ctx[n,kg,v] / ksum[n,kg]  (tiny)
//  K4 k_out     : out = M[n] @ qsm + br   (one 96x96 channel matmul).

#define NV 131072
#define CC 96
#define NB 2

// ---------------------------------------------------------------- kernel 1
__global__ __launch_bounds__(256) void k_proj_kq(
    const float* __restrict__ x,
    const float* __restrict__ Wk, const float* __restrict__ bk,
    const float* __restrict__ Wq, const float* __restrict__ bq,
    float* __restrict__ expk, float* __restrict__ qsm,
    float* __restrict__ ksum)
{
    __shared__ float qb[24 * 256];   // per-thread private columns, no sync needed
    const int tid = threadIdx.x;
    const int n = blockIdx.x >> 9;                 // 512 blocks per n
    const int p = ((blockIdx.x & 511) << 8) + tid; // 256 positions per block
    const size_t base = (size_t)n * CC * NV + (size_t)p;

    float xr[CC];
#pragma unroll
    for (int c = 0; c < CC; ++c) xr[c] = x[base + (size_t)c * NV];

    // ---- queries: per-head softmax over the 24 head channels
    for (int h = 0; h < 4; ++h) {
        for (int j = 0; j < 24; ++j) {
            const int o = h * 24 + j;
            const float* __restrict__ wr = Wq + o * CC;
            float a = bq[o];
#pragma unroll
            for (int c = 0; c < CC; ++c) a = fmaf(wr[c], xr[c], a);
            qb[j * 256 + tid] = a;
        }
        float mx = -1e30f;
        for (int j = 0; j < 24; ++j) mx = fmaxf(mx, qb[j * 256 + tid]);
        float s = 0.f;
        for (int j = 0; j < 24; ++j) {
            const float e = __expf(qb[j * 256 + tid] - mx);
            qb[j * 256 + tid] = e;
            s += e;
        }
        const float inv = 1.f / s;
        for (int j = 0; j < 24; ++j)
            qsm[base + (size_t)(h * 24 + j) * NV] = qb[j * 256 + tid] * inv;
    }

    // ---- keys: write exp(keys), accumulate per-channel sums (wave reduce + atomic)
    for (int o = 0; o < CC; ++o) {
        const float* __restrict__ wr = Wk + o * CC;
        float a = bk[o];
#pragma unroll
        for (int c = 0; c < CC; ++c) a = fmaf(wr[c], xr[c], a);
        const float e = __expf(a);   // |keys| small -> safe without max subtraction
        expk[base + (size_t)o * NV] = e;
        float w = e;
#pragma unroll
        for (int off = 32; off > 0; off >>= 1) w += __shfl_down(w, off, 64);
        if ((tid & 63) == 0) atomicAdd(&ksum[n * CC + o], w);
    }
}

// ---------------------------------------------------------------- kernel 2
// Block: 256 threads, fixed n, 4 tiles of 64 positions each (256 positions/block).
// LDS: xs (x tile, later reused as expk tile), vsh (computed V tile). Rows padded
// to 68 floats to break the stride-64 bank pattern in phase B.
__global__ __launch_bounds__(256) void k_ctx(
    const float* __restrict__ x,
    const float* __restrict__ Wv, const float* __restrict__ bv,
    const float* __restrict__ expk,
    float* __restrict__ ctx)
{
    __shared__ float xs[CC * 68];
    __shared__ float vsh[CC * 68];
    const int tid = threadIdx.x;
    const int n = blockIdx.x >> 9;
    const int blk = blockIdx.x & 511;
    const int pl = tid & 63;   // position within tile
    const int g = tid >> 6;    // wave id -> V channel group (24 channels each)

    int kg9[9], vv9[9];
    float acc[9];
#pragma unroll
    for (int k = 0; k < 9; ++k) {
        const int pr = tid + 256 * k;   // (kg, v) pair index, 96*24 = 2304 total
        kg9[k] = pr / 24;
        vv9[k] = pr % 24;
        acc[k] = 0.f;
    }

    for (int t = 0; t < 4; ++t) {
        const int p0 = (blk * 4 + t) * 64;
        __syncthreads();   // prev tile's phase B done before overwriting LDS
        // load x tile [96][64] -> xs
        for (int idx = tid; idx < CC * 16; idx += 256) {
            const int row = idx >> 4, c4 = idx & 15;
            ((float4*)xs)[row * 17 + c4] =
                ((const float4*)(x + (size_t)(n * CC + row) * NV + p0))[c4];
        }
        __syncthreads();
        // phase A: V projection, wave g computes channels [g*24, g*24+24) for its 64 positions
        float vacc[24];
#pragma unroll
        for (int j = 0; j < 24; ++j) vacc[j] = bv[g * 24 + j];
        for (int c = 0; c < CC; ++c) {
            const float xv = xs[c * 68 + pl];
            const float* __restrict__ wv = Wv + (g * 24) * CC + c;
#pragma unroll
            for (int j = 0; j < 24; ++j) vacc[j] = fmaf(wv[j * CC], xv, vacc[j]);
        }
#pragma unroll
        for (int j = 0; j < 24; ++j) vsh[(g * 24 + j) * 68 + pl] = vacc[j];
        __syncthreads();   // all xs reads done -> safe to overwrite with expk
        // load expk tile -> xs
        for (int idx = tid; idx < CC * 16; idx += 256) {
            const int row = idx >> 4, c4 = idx & 15;
            ((float4*)xs)[row * 17 + c4] =
                ((const float4*)(expk + (size_t)(n * CC + row) * NV + p0))[c4];
        }
        __syncthreads();
        // phase B: outer-product accumulation over the 64 positions
#pragma unroll
        for (int k = 0; k < 9; ++k) {
            const float4* __restrict__ er = (const float4*)(xs + kg9[k] * 68);
            const int h = kg9[k] / 24;
            const float4* __restrict__ vr = (const float4*)(vsh + (h * 24 + vv9[k]) * 68);
            float a = 0.f;
#pragma unroll
            for (int q = 0; q < 16; ++q) {
                const float4 e4 = er[q];
                const float4 v4 = vr[q];
                a = fmaf(e4.x, v4.x, a);
                a = fmaf(e4.y, v4.y, a);
                a = fmaf(e4.z, v4.z, a);
                a = fmaf(e4.w, v4.w, a);
            }
            acc[k] += a;
        }
    }
#pragma unroll
    for (int k = 0; k < 9; ++k)
        atomicAdd(&ctx[((size_t)n * CC + kg9[k]) * 24 + vv9[k]], acc[k]);
}

// ---------------------------------------------------------------- kernel 3
__global__ __launch_bounds__(256) void k_combine(
    const float* __restrict__ Wr, const float* __restrict__ ctx,
    const float* __restrict__ ksum, float* __restrict__ Mn)
{
    const int n = blockIdx.x;
    for (int i = threadIdx.x; i < CC * CC; i += 256) {
        const int o = i / CC, kg = i % CC, h = kg / 24;
        float a = 0.f;
        for (int v = 0; v < 24; ++v)
            a += Wr[o * CC + h * 24 + v] * ctx[((size_t)n * CC + kg) * 24 + v];
        Mn[((size_t)n * CC + o) * CC + kg] = a / ksum[n * CC + kg];
    }
}

// ---------------------------------------------------------------- kernel 4
__global__ __launch_bounds__(256) void k_out(
    const float* __restrict__ qsm, const float* __restrict__ Mn,
    const float* __restrict__ br, float* __restrict__ out)
{
    const int tid = threadIdx.x;
    const int n = blockIdx.x >> 9;
    const int p = ((blockIdx.x & 511) << 8) + tid;
    const size_t base = (size_t)n * CC * NV + (size_t)p;

    float qr[CC];
#pragma unroll
    for (int c = 0; c < CC; ++c) qr[c] = qsm[base + (size_t)c * NV];

    const float* __restrict__ Mb = Mn + n * CC * CC;
    for (int o = 0; o < CC; ++o) {
        float a = br[o];
        const float* __restrict__ mr = Mb + o * CC;
#pragma unroll
        for (int c = 0; c < CC; ++c) a = fmaf(mr[c], qr[c], a);
        out[base + (size_t)o * NV] = a;
    }
}

// ---------------------------------------------------------------- launch
extern "C" void kernel_launch(void* const* d_in, const int* in_sizes, int n_in,
                              void* d_out, int out_size, void* d_ws, size_t ws_size,
                              hipStream_t stream) {
    const float* x  = (const float*)d_in[0];
    const float* Wk = (const float*)d_in[1];
    const float* bk = (const float*)d_in[2];
    const float* Wq = (const float*)d_in[3];
    const float* bq = (const float*)d_in[4];
    const float* Wv = (const float*)d_in[5];
    const float* bv = (const float*)d_in[6];
    const float* Wr = (const float*)d_in[7];
    const float* br = (const float*)d_in[8];
    float* out = (float*)d_out;

    float* ws = (float*)d_ws;
    const size_t BIG = (size_t)NB * CC * NV;   // 25,165,824 floats
    float* expk = ws;                          // [2,96,NV]
    float* qsm  = ws + BIG;                    // [2,96,NV]
    float* ctx  = ws + 2 * BIG;                // [2,96,24] = 4608
    float* ksum = ctx + (size_t)NB * CC * 24;  // [2,96]    = 192
    float* Mn   = ksum + (size_t)NB * CC;      // [2,96,96] = 18432

    // zero the atomic accumulators (ws is poisoned 0xAA before every call)
    hipMemsetAsync(ctx, 0, ((size_t)NB * CC * 24 + (size_t)NB * CC) * sizeof(float), stream);

    k_proj_kq<<<dim3(NB * 512), dim3(256), 0, stream>>>(x, Wk, bk, Wq, bq, expk, qsm, ksum);
    k_ctx<<<dim3(NB * 512), dim3(256), 0, stream>>>(x, Wv, bv, expk, ctx);
    k_combine<<<dim3(NB), dim3(256), 0, stream>>>(Wr, ctx, ksum, Mn);
    k_out<<<dim3(NB * 512), dim3(256), 0, stream>>>(qsm, Mn, br, out);
}

// Round 2
// 1872.387 us; speedup vs baseline: 1.5662x; 1.5662x over previous
//
#include <hip/hip_runtime.h>

// EfficientAttention on MI355X — round 2: fused fp32 pipeline, ILP-restructured.
// Shapes: N=2, C=96, Nvox=131072 (32*64*64), HEADS=4, hk=hv=24.
//
//  K1 k_fused   : per block: 256 positions (4 tiles x 64). Per tile: stage x in
//                 LDS; wave g = head g, lane = position. Phase Q (24 acc, softmax
//                 in regs, write qsm), phase V (24 acc -> LDS), phase K (24 acc,
//                 exp -> LDS reusing x-tile; per-lane ksum partials), phase B
//                 (context outer product, 9 acc/lane across tiles). Atomics once
//                 at block end. No expk round-trip through HBM.
//  K2 k_combine : M[n][o][kg] = sum_v Wr[o,h*24+v] * ctx[n,kg,v] / ksum[n,kg].
//  K3 k_out     : out = M[n] @ qsm + br, 8-way output grouping for ILP.

#define NV 131072
#define CC 96
#define NB 2
#define HK 24

// ---------------------------------------------------------------- kernel 1
__global__ __launch_bounds__(256) void k_fused(
    const float* __restrict__ x,
    const float* __restrict__ Wk, const float* __restrict__ bk,
    const float* __restrict__ Wq, const float* __restrict__ bq,
    const float* __restrict__ Wv, const float* __restrict__ bv,
    float* __restrict__ qsm, float* __restrict__ ctx, float* __restrict__ ksum)
{
    __shared__ float xs[CC * 68];   // x tile [96][64] (pad 68); reused as exp(k) tile
    __shared__ float vsh[CC * 68];  // v tile [96][64] (row = h*24+j)
    const int tid = threadIdx.x;
    const int n   = blockIdx.x >> 9;
    const int blk = blockIdx.x & 511;
    const int pl  = tid & 63;   // lane = position within tile
    const int g   = tid >> 6;   // wave = head

    const float* __restrict__ Wqh = Wq + g * HK * CC;
    const float* __restrict__ Wvh = Wv + g * HK * CC;
    const float* __restrict__ Wkh = Wk + g * HK * CC;

    float ksum_l[HK];           // per-lane partial key-sums (reduced once at end)
    float cacc[9];              // context accumulators: 576 (kg,v) pairs / 64 lanes
    int kg9[9], vv9[9];
#pragma unroll
    for (int j = 0; j < HK; ++j) ksum_l[j] = 0.f;
#pragma unroll
    for (int k = 0; k < 9; ++k) {
        const int pr = pl + 64 * k;      // covers 0..575 exactly
        kg9[k] = pr / 24;
        vv9[k] = pr % 24;
        cacc[k] = 0.f;
    }

    for (int t = 0; t < 4; ++t) {
        const int p0 = (blk * 4 + t) * 64;
        const size_t xbase = (size_t)n * CC * NV + (size_t)p0;
        __syncthreads();   // prev tile phase B done before overwriting LDS
        for (int idx = tid; idx < CC * 16; idx += 256) {
            const int row = idx >> 4, c4 = idx & 15;
            ((float4*)xs)[row * 17 + c4] =
                ((const float4*)(x + xbase + (size_t)row * NV))[c4];
        }
        __syncthreads();

        // ---- phase Q: 24 channels for head g, softmax in registers
        {
            float acc[HK];
#pragma unroll
            for (int j = 0; j < HK; ++j) acc[j] = bq[g * HK + j];
#pragma unroll 4
            for (int c = 0; c < CC; ++c) {
                const float xv = xs[c * 68 + pl];
#pragma unroll
                for (int j = 0; j < HK; ++j) acc[j] = fmaf(Wqh[j * CC + c], xv, acc[j]);
            }
            float mx = acc[0];
#pragma unroll
            for (int j = 1; j < HK; ++j) mx = fmaxf(mx, acc[j]);
            float s = 0.f;
#pragma unroll
            for (int j = 0; j < HK; ++j) { acc[j] = __expf(acc[j] - mx); s += acc[j]; }
            const float inv = 1.f / s;
            const size_t qbase = (size_t)n * CC * NV + (size_t)(g * HK) * NV + p0 + pl;
#pragma unroll
            for (int j = 0; j < HK; ++j) qsm[qbase + (size_t)j * NV] = acc[j] * inv;
        }

        // ---- phase V: 24 channels for head g -> vsh
        {
            float acc[HK];
#pragma unroll
            for (int j = 0; j < HK; ++j) acc[j] = bv[g * HK + j];
#pragma unroll 4
            for (int c = 0; c < CC; ++c) {
                const float xv = xs[c * 68 + pl];
#pragma unroll
                for (int j = 0; j < HK; ++j) acc[j] = fmaf(Wvh[j * CC + c], xv, acc[j]);
            }
#pragma unroll
            for (int j = 0; j < HK; ++j) vsh[(g * HK + j) * 68 + pl] = acc[j];
        }

        // ---- phase K: 24 channels, exp, write into xs (reuse), ksum partials
        {
            float acc[HK];
#pragma unroll
            for (int j = 0; j < HK; ++j) acc[j] = bk[g * HK + j];
#pragma unroll 4
            for (int c = 0; c < CC; ++c) {
                const float xv = xs[c * 68 + pl];
#pragma unroll
                for (int j = 0; j < HK; ++j) acc[j] = fmaf(Wkh[j * CC + c], xv, acc[j]);
            }
#pragma unroll
            for (int j = 0; j < HK; ++j) { acc[j] = __expf(acc[j]); ksum_l[j] += acc[j]; }
            __syncthreads();   // everyone done reading xs as x-tile
#pragma unroll
            for (int j = 0; j < HK; ++j) xs[(g * HK + j) * 68 + pl] = acc[j];
        }
        __syncthreads();

        // ---- phase B: context outer product over 64 positions
#pragma unroll
        for (int k = 0; k < 9; ++k) {
            const float4* __restrict__ er = (const float4*)(xs + (g * HK + kg9[k]) * 68);
            const float4* __restrict__ vr = (const float4*)(vsh + (g * HK + vv9[k]) * 68);
            float a = 0.f;
#pragma unroll
            for (int q = 0; q < 16; ++q) {
                const float4 e4 = er[q];
                const float4 v4 = vr[q];
                a = fmaf(e4.x, v4.x, a);
                a = fmaf(e4.y, v4.y, a);
                a = fmaf(e4.z, v4.z, a);
                a = fmaf(e4.w, v4.w, a);
            }
            cacc[k] += a;
        }
    }

    // ---- block-end reductions
#pragma unroll
    for (int k = 0; k < 9; ++k)
        atomicAdd(&ctx[((size_t)n * CC + g * HK + kg9[k]) * 24 + vv9[k]], cacc[k]);
#pragma unroll
    for (int j = 0; j < HK; ++j) {
        float w = ksum_l[j];
#pragma unroll
        for (int off = 32; off > 0; off >>= 1) w += __shfl_down(w, off, 64);
        if (pl == 0) atomicAdd(&ksum[n * CC + g * HK + j], w);
    }
}

// ---------------------------------------------------------------- kernel 2
__global__ __launch_bounds__(256) void k_combine(
    const float* __restrict__ Wr, const float* __restrict__ ctx,
    const float* __restrict__ ksum, float* __restrict__ Mn)
{
    const int n = blockIdx.x;
    for (int i = threadIdx.x; i < CC * CC; i += 256) {
        const int o = i / CC, kg = i % CC, h = kg / 24;
        float a = 0.f;
        for (int v = 0; v < 24; ++v)
            a += Wr[o * CC + h * 24 + v] * ctx[((size_t)n * CC + kg) * 24 + v];
        Mn[((size_t)n * CC + o) * CC + kg] = a / ksum[n * CC + kg];
    }
}

// ---------------------------------------------------------------- kernel 3
__global__ __launch_bounds__(256) void k_out(
    const float* __restrict__ qsm, const float* __restrict__ Mn,
    const float* __restrict__ br, float* __restrict__ out)
{
    const int tid = threadIdx.x;
    const int n = blockIdx.x >> 9;
    const int p = ((blockIdx.x & 511) << 8) + tid;
    const size_t base = (size_t)n * CC * NV + (size_t)p;

    float qr[CC];
#pragma unroll
    for (int c = 0; c < CC; ++c) qr[c] = qsm[base + (size_t)c * NV];

    const float* __restrict__ Mb = Mn + n * CC * CC;
#pragma unroll 1
    for (int og = 0; og < CC; og += 8) {
        float a[8];
#pragma unroll
        for (int j = 0; j < 8; ++j) a[j] = br[og + j];
#pragma unroll
        for (int c = 0; c < CC; ++c) {
            const float q = qr[c];
#pragma unroll
            for (int j = 0; j < 8; ++j) a[j] = fmaf(Mb[(og + j) * CC + c], q, a[j]);
        }
#pragma unroll
        for (int j = 0; j < 8; ++j) out[base + (size_t)(og + j) * NV] = a[j];
    }
}

// ---------------------------------------------------------------- launch
extern "C" void kernel_launch(void* const* d_in, const int* in_sizes, int n_in,
                              void* d_out, int out_size, void* d_ws, size_t ws_size,
                              hipStream_t stream) {
    const float* x  = (const float*)d_in[0];
    const float* Wk = (const float*)d_in[1];
    const float* bk = (const float*)d_in[2];
    const float* Wq = (const float*)d_in[3];
    const float* bq = (const float*)d_in[4];
    const float* Wv = (const float*)d_in[5];
    const float* bv = (const float*)d_in[6];
    const float* Wr = (const float*)d_in[7];
    const float* br = (const float*)d_in[8];
    float* out = (float*)d_out;

    float* ws = (float*)d_ws;
    const size_t BIG = (size_t)NB * CC * NV;   // 25,165,824 floats
    float* qsm  = ws;                          // [2,96,NV]
    float* ctx  = ws + BIG;                    // [2,96,24] = 4608
    float* ksum = ctx + (size_t)NB * CC * 24;  // [2,96]    = 192
    float* Mn   = ksum + (size_t)NB * CC;      // [2,96,96] = 18432

    // zero the atomic accumulators (ws is poisoned 0xAA before every call)
    hipMemsetAsync(ctx, 0, ((size_t)NB * CC * 24 + (size_t)NB * CC) * sizeof(float), stream);

    k_fused<<<dim3(NB * 512), dim3(256), 0, stream>>>(x, Wk, bk, Wq, bq, Wv, bv, qsm, ctx, ksum);
    k_combine<<<dim3(NB), dim3(256), 0, stream>>>(Wr, ctx, ksum, Mn);
    k_out<<<dim3(NB * 512), dim3(256), 0, stream>>>(qsm, Mn, br, out);
}

// Round 3
// 947.593 us; speedup vs baseline: 3.0948x; 1.9759x over previous
//
#include <hip/hip_runtime.h>

// EfficientAttention on MI355X — round 3: scalar-path weights (s_load via
// readfirstlane-uniform pointers) so the FMA loops are VALU-bound, not
// VMEM-issue-bound. 8 tiles/block for an even 2-blocks/CU grid.
//
//  K1 k_fused   : per block: 512 positions (8 tiles x 64). Per tile: stage x in
//                 LDS; wave g = head g, lane = position. Phase Q (24 acc, softmax
//                 in regs, write qsm), phase V (24 acc -> LDS), phase K (24 acc,
//                 exp -> LDS reusing x-tile; per-lane ksum partials), phase B
//                 (context outer product, 9 acc/lane). Atomics once per block.
//  K2 k_combine : M[n][o][kg] = sum_v Wr[o,h*24+v] * ctx[n,kg,v] / ksum[n,kg].
//  K3 k_out     : out = M[n] @ qsm + br, 8-way output grouping for ILP.

#define NV 131072
#define CC 96
#define NB 2
#define HK 24
#define TPB 8                 // 64-position tiles per block
#define BPN (NV / (64 * TPB)) // 256 blocks per batch index

// ---------------------------------------------------------------- kernel 1
__global__ __launch_bounds__(256) void k_fused(
    const float* __restrict__ x,
    const float* __restrict__ Wk, const float* __restrict__ bk,
    const float* __restrict__ Wq, const float* __restrict__ bq,
    const float* __restrict__ Wv, const float* __restrict__ bv,
    float* __restrict__ qsm, float* __restrict__ ctx, float* __restrict__ ksum)
{
    __shared__ float xs[CC * 68];   // x tile [96][64] (pad 68); reused as exp(k) tile
    __shared__ float vsh[CC * 68];  // v tile [96][64] (row = h*24+j)
    const int tid = threadIdx.x;
    const int n   = blockIdx.x >> 8;
    const int blk = blockIdx.x & 255;
    const int pl  = tid & 63;   // lane = position within tile
    const int g   = tid >> 6;   // wave = head
    // Force the head index wave-uniform -> all weight/bias addresses are
    // scalar -> compiler emits s_load + scalar-operand v_fma (VMEM pipe freed).
    const int gu  = __builtin_amdgcn_readfirstlane(g);

    const float* __restrict__ Wqh = Wq + gu * HK * CC;
    const float* __restrict__ Wvh = Wv + gu * HK * CC;
    const float* __restrict__ Wkh = Wk + gu * HK * CC;
    const float* __restrict__ bqh = bq + gu * HK;
    const float* __restrict__ bvh = bv + gu * HK;
    const float* __restrict__ bkh = bk + gu * HK;

    float ksum_l[HK];           // per-lane partial key-sums
    float cacc[9];              // context accumulators: 576 (kg,v) pairs / 64 lanes
    int kg9[9], vv9[9];
#pragma unroll
    for (int j = 0; j < HK; ++j) ksum_l[j] = 0.f;
#pragma unroll
    for (int k = 0; k < 9; ++k) {
        const int pr = pl + 64 * k;      // covers 0..575 exactly
        kg9[k] = pr / 24;
        vv9[k] = pr % 24;
        cacc[k] = 0.f;
    }

    for (int t = 0; t < TPB; ++t) {
        const int p0 = (blk * TPB + t) * 64;
        const size_t xbase = (size_t)n * CC * NV + (size_t)p0;
        __syncthreads();   // prev tile phase B done before overwriting LDS
        for (int idx = tid; idx < CC * 16; idx += 256) {
            const int row = idx >> 4, c4 = idx & 15;
            ((float4*)xs)[row * 17 + c4] =
                ((const float4*)(x + xbase + (size_t)row * NV))[c4];
        }
        __syncthreads();

        // ---- phase Q: 24 channels for head g, softmax in registers
        {
            float acc[HK];
#pragma unroll
            for (int j = 0; j < HK; ++j) acc[j] = bqh[j];
#pragma unroll 4
            for (int c = 0; c < CC; ++c) {
                const float xv = xs[c * 68 + pl];
#pragma unroll
                for (int j = 0; j < HK; ++j) acc[j] = fmaf(Wqh[j * CC + c], xv, acc[j]);
            }
            float mx = acc[0];
#pragma unroll
            for (int j = 1; j < HK; ++j) mx = fmaxf(mx, acc[j]);
            float s = 0.f;
#pragma unroll
            for (int j = 0; j < HK; ++j) { acc[j] = __expf(acc[j] - mx); s += acc[j]; }
            const float inv = 1.f / s;
            const size_t qbase = (size_t)n * CC * NV + (size_t)(gu * HK) * NV + p0 + pl;
#pragma unroll
            for (int j = 0; j < HK; ++j) qsm[qbase + (size_t)j * NV] = acc[j] * inv;
        }

        // ---- phase V: 24 channels for head g -> vsh
        {
            float acc[HK];
#pragma unroll
            for (int j = 0; j < HK; ++j) acc[j] = bvh[j];
#pragma unroll 4
            for (int c = 0; c < CC; ++c) {
                const float xv = xs[c * 68 + pl];
#pragma unroll
                for (int j = 0; j < HK; ++j) acc[j] = fmaf(Wvh[j * CC + c], xv, acc[j]);
            }
#pragma unroll
            for (int j = 0; j < HK; ++j) vsh[(gu * HK + j) * 68 + pl] = acc[j];
        }

        // ---- phase K: 24 channels, exp, write into xs (reuse), ksum partials
        {
            float acc[HK];
#pragma unroll
            for (int j = 0; j < HK; ++j) acc[j] = bkh[j];
#pragma unroll 4
            for (int c = 0; c < CC; ++c) {
                const float xv = xs[c * 68 + pl];
#pragma unroll
                for (int j = 0; j < HK; ++j) acc[j] = fmaf(Wkh[j * CC + c], xv, acc[j]);
            }
#pragma unroll
            for (int j = 0; j < HK; ++j) { acc[j] = __expf(acc[j]); ksum_l[j] += acc[j]; }
            __syncthreads();   // everyone done reading xs as x-tile
#pragma unroll
            for (int j = 0; j < HK; ++j) xs[(gu * HK + j) * 68 + pl] = acc[j];
        }
        __syncthreads();

        // ---- phase B: context outer product over 64 positions
#pragma unroll
        for (int k = 0; k < 9; ++k) {
            const float4* __restrict__ er = (const float4*)(xs + (gu * HK + kg9[k]) * 68);
            const float4* __restrict__ vr = (const float4*)(vsh + (gu * HK + vv9[k]) * 68);
            float a = 0.f;
#pragma unroll
            for (int q = 0; q < 16; ++q) {
                const float4 e4 = er[q];
                const float4 v4 = vr[q];
                a = fmaf(e4.x, v4.x, a);
                a = fmaf(e4.y, v4.y, a);
                a = fmaf(e4.z, v4.z, a);
                a = fmaf(e4.w, v4.w, a);
            }
            cacc[k] += a;
        }
    }

    // ---- block-end reductions
#pragma unroll
    for (int k = 0; k < 9; ++k)
        atomicAdd(&ctx[((size_t)n * CC + gu * HK + kg9[k]) * 24 + vv9[k]], cacc[k]);
#pragma unroll
    for (int j = 0; j < HK; ++j) {
        float w = ksum_l[j];
#pragma unroll
        for (int off = 32; off > 0; off >>= 1) w += __shfl_down(w, off, 64);
        if (pl == 0) atomicAdd(&ksum[n * CC + gu * HK + j], w);
    }
}

// ---------------------------------------------------------------- kernel 2
__global__ __launch_bounds__(256) void k_combine(
    const float* __restrict__ Wr, const float* __restrict__ ctx,
    const float* __restrict__ ksum, float* __restrict__ Mn)
{
    const int n = blockIdx.x;
    for (int i = threadIdx.x; i < CC * CC; i += 256) {
        const int o = i / CC, kg = i % CC, h = kg / 24;
        float a = 0.f;
        for (int v = 0; v < 24; ++v)
            a += Wr[o * CC + h * 24 + v] * ctx[((size_t)n * CC + kg) * 24 + v];
        Mn[((size_t)n * CC + o) * CC + kg] = a / ksum[n * CC + kg];
    }
}

// ---------------------------------------------------------------- kernel 3
__global__ __launch_bounds__(256) void k_out(
    const float* __restrict__ qsm, const float* __restrict__ Mn,
    const float* __restrict__ br, float* __restrict__ out)
{
    const int tid = threadIdx.x;
    const int n = blockIdx.x >> 9;
    const int p = ((blockIdx.x & 511) << 8) + tid;
    const size_t base = (size_t)n * CC * NV + (size_t)p;

    float qr[CC];
#pragma unroll
    for (int c = 0; c < CC; ++c) qr[c] = qsm[base + (size_t)c * NV];

    // Mn base is blockIdx-derived -> scalar -> weight loads go down the SMEM path.
    const float* __restrict__ Mb = Mn + n * CC * CC;
#pragma unroll 1
    for (int og = 0; og < CC; og += 8) {
        float a[8];
#pragma unroll
        for (int j = 0; j < 8; ++j) a[j] = br[og + j];
#pragma unroll 4
        for (int c = 0; c < CC; ++c) {
            const float q = qr[c];
#pragma unroll
            for (int j = 0; j < 8; ++j) a[j] = fmaf(Mb[(og + j) * CC + c], q, a[j]);
        }
#pragma unroll
        for (int j = 0; j < 8; ++j) out[base + (size_t)(og + j) * NV] = a[j];
    }
}

// ---------------------------------------------------------------- launch
extern "C" void kernel_launch(void* const* d_in, const int* in_sizes, int n_in,
                              void* d_out, int out_size, void* d_ws, size_t ws_size,
                              hipStream_t stream) {
    const float* x  = (const float*)d_in[0];
    const float* Wk = (const float*)d_in[1];
    const float* bk = (const float*)d_in[2];
    const float* Wq = (const float*)d_in[3];
    const float* bq = (const float*)d_in[4];
    const float* Wv = (const float*)d_in[5];
    const float* bv = (const float*)d_in[6];
    const float* Wr = (const float*)d_in[7];
    const float* br = (const float*)d_in[8];
    float* out = (float*)d_out;

    float* ws = (float*)d_ws;
    const size_t BIG = (size_t)NB * CC * NV;   // 25,165,824 floats
    float* qsm  = ws;                          // [2,96,NV]
    float* ctx  = ws + BIG;                    // [2,96,24] = 4608
    float* ksum = ctx + (size_t)NB * CC * 24;  // [2,96]    = 192
    float* Mn   = ksum + (size_t)NB * CC;      // [2,96,96] = 18432

    // zero the atomic accumulators (ws is poisoned 0xAA before every call)
    hipMemsetAsync(ctx, 0, ((size_t)NB * CC * 24 + (size_t)NB * CC) * sizeof(float), stream);

    k_fused<<<dim3(NB * BPN), dim3(256), 0, stream>>>(x, Wk, bk, Wq, bq, Wv, bv, qsm, ctx, ksum);
    k_combine<<<dim3(NB), dim3(256), 0, stream>>>(Wr, ctx, ksum, Mn);
    k_out<<<dim3(NB * 512), dim3(256), 0, stream>>>(qsm, Mn, br, out);
}

// Round 4
// 720.364 us; speedup vs baseline: 4.0710x; 1.3154x over previous
//
#include <hip/hip_runtime.h>

// EfficientAttention MI355X — round 4: barrier-free k_fused, transposed weights
// (contiguous s_load path), register-resident x chunks, 3x3 phase-B tile.
//
//  K0 k_prep    : Wt[h][c][j] = W[h*24+j][c] for Wq/Wk/Wv (one tiny launch).
//  K1 k_fused   : grid-stride tiles of 64 positions; wave = head; no barriers.
//                 Per tile: x in reg chunks -> 72 simultaneous Q/K/V accums;
//                 q-softmax in regs -> qsm; exp(k), v -> per-wave LDS;
//                 ksum row-sum; 3x3 context outer-product into 9 regs.
//                 One atomic flush per block at the end.
//  K2 k_combine : Mnt[n][kg][o] = sum_v Wr[o,h*24+v]*ctx[n,kg,v]/ksum[n,kg].
//  K3 k_out     : out = M[n] @ qsm + br with 96 accumulators, contiguous s_loads.

#define NV 131072
#define CC 96
#define NB 2
#define HK 24
#define PAD 68
#define BPN 384          // k_fused blocks per batch index
#define TILES_N 2048     // 64-position tiles per batch index

// ---------------------------------------------------------------- kernel 0
__global__ __launch_bounds__(256) void k_prep(
    const float* __restrict__ Wq, const float* __restrict__ Wk,
    const float* __restrict__ Wv,
    float* __restrict__ Wqt, float* __restrict__ Wkt, float* __restrict__ Wvt)
{
    const int i = blockIdx.x * 256 + threadIdx.x;
    if (i >= CC * CC) return;
    const int h = i / (HK * CC);
    const int r = i % (HK * CC);
    const int c = r / HK;
    const int j = r % HK;
    const int src = (h * HK + j) * CC + c;
    Wqt[i] = Wq[src];
    Wkt[i] = Wk[src];
    Wvt[i] = Wv[src];
}

// ---------------------------------------------------------------- kernel 1
__global__ __launch_bounds__(256) void k_fused(
    const float* __restrict__ x,
    const float* __restrict__ Wqt, const float* __restrict__ bq,
    const float* __restrict__ Wkt, const float* __restrict__ bk,
    const float* __restrict__ Wvt, const float* __restrict__ bv,
    float* __restrict__ qsm, float* __restrict__ ctx, float* __restrict__ ksum)
{
    __shared__ float eks[4 * HK * PAD];   // per-wave exp(k) tiles [24][68]
    __shared__ float vls[4 * HK * PAD];   // per-wave v tiles      [24][68]
    const int tid = threadIdx.x;
    const int pl  = tid & 63;
    const int gu  = __builtin_amdgcn_readfirstlane(tid >> 6);  // wave = head
    const int n   = blockIdx.x / BPN;
    const int r0  = blockIdx.x % BPN;
    const int a   = pl >> 3, b = pl & 7;  // 8x8 lane grid for 3x3 ctx tile

    float* __restrict__ ek = eks + gu * HK * PAD;
    float* __restrict__ vl = vls + gu * HK * PAD;
    const float* __restrict__ Wqh = Wqt + gu * HK * CC;  // [c][j] contiguous
    const float* __restrict__ Wkh = Wkt + gu * HK * CC;
    const float* __restrict__ Wvh = Wvt + gu * HK * CC;

    float cacc[9];
#pragma unroll
    for (int k = 0; k < 9; ++k) cacc[k] = 0.f;
    float ksacc = 0.f;

    for (int tt = r0; tt < TILES_N; tt += BPN) {
        const size_t xb = (size_t)n * CC * NV + (size_t)tt * 64 + pl;

        // ---- projections: 72 simultaneous accumulators, x in 16-reg chunks
        float aq[HK], ak[HK], av[HK];
#pragma unroll
        for (int j = 0; j < HK; ++j) {
            aq[j] = bq[gu * HK + j];
            ak[j] = bk[gu * HK + j];
            av[j] = bv[gu * HK + j];
        }
        for (int ch = 0; ch < 6; ++ch) {
            float xr[16];
#pragma unroll
            for (int u = 0; u < 16; ++u)
                xr[u] = x[xb + (size_t)(ch * 16 + u) * NV];
#pragma unroll
            for (int u = 0; u < 16; ++u) {
                const int c = ch * 16 + u;
#pragma unroll
                for (int j = 0; j < HK; ++j) {
                    aq[j] = fmaf(Wqh[c * HK + j], xr[u], aq[j]);
                    ak[j] = fmaf(Wkh[c * HK + j], xr[u], ak[j]);
                    av[j] = fmaf(Wvh[c * HK + j], xr[u], av[j]);
                }
            }
        }

        // ---- q softmax (registers) -> qsm
        {
            float mx = aq[0];
#pragma unroll
            for (int j = 1; j < HK; ++j) mx = fmaxf(mx, aq[j]);
            float s = 0.f;
#pragma unroll
            for (int j = 0; j < HK; ++j) { aq[j] = __expf(aq[j] - mx); s += aq[j]; }
            const float inv = 1.f / s;
            const size_t qb = ((size_t)n * CC + gu * HK) * NV + (size_t)tt * 64 + pl;
#pragma unroll
            for (int j = 0; j < HK; ++j)
                qsm[qb + (size_t)j * NV] = aq[j] * inv;
        }

        // ---- exp(k) and v into this wave's private LDS (no barrier needed)
#pragma unroll
        for (int j = 0; j < HK; ++j) ek[j * PAD + pl] = __expf(ak[j]);
#pragma unroll
        for (int j = 0; j < HK; ++j) vl[j * PAD + pl] = av[j];

        // ---- ksum: lane < 24 sums its exp(k) row
        if (pl < HK) {
            const float4* __restrict__ rp = (const float4*)(ek + pl * PAD);
            float s = 0.f;
#pragma unroll
            for (int q = 0; q < 16; ++q) {
                const float4 t = rp[q];
                s += t.x + t.y + t.z + t.w;
            }
            ksacc += s;
        }

        // ---- context outer product: 3x3 register tile per lane
#pragma unroll
        for (int q = 0; q < 16; ++q) {
            float4 e4[3], v4[3];
#pragma unroll
            for (int i = 0; i < 3; ++i)
                e4[i] = ((const float4*)(ek + (a + 8 * i) * PAD))[q];
#pragma unroll
            for (int j = 0; j < 3; ++j)
                v4[j] = ((const float4*)(vl + (b + 8 * j) * PAD))[q];
#pragma unroll
            for (int i = 0; i < 3; ++i)
#pragma unroll
                for (int j = 0; j < 3; ++j) {
                    float t = cacc[i * 3 + j];
                    t = fmaf(e4[i].x, v4[j].x, t);
                    t = fmaf(e4[i].y, v4[j].y, t);
                    t = fmaf(e4[i].z, v4[j].z, t);
                    t = fmaf(e4[i].w, v4[j].w, t);
                    cacc[i * 3 + j] = t;
                }
        }
    }

    // ---- one atomic flush per block
#pragma unroll
    for (int i = 0; i < 3; ++i)
#pragma unroll
        for (int j = 0; j < 3; ++j)
            atomicAdd(&ctx[((size_t)n * CC + gu * HK + a + 8 * i) * HK + b + 8 * j],
                      cacc[i * 3 + j]);
    if (pl < HK) atomicAdd(&ksum[n * CC + gu * HK + pl], ksacc);
}

// ---------------------------------------------------------------- kernel 2
// Mnt[n][kg][o] (transposed so k_out's per-c row is 96 contiguous floats)
__global__ __launch_bounds__(256) void k_combine(
    const float* __restrict__ Wr, const float* __restrict__ ctx,
    const float* __restrict__ ksum, float* __restrict__ Mnt)
{
    const int n = blockIdx.x;
    for (int i = threadIdx.x; i < CC * CC; i += 256) {
        const int kg = i / CC, o = i % CC, h = kg / HK;
        float a = 0.f;
        for (int v = 0; v < HK; ++v)
            a += Wr[o * CC + h * HK + v] * ctx[((size_t)n * CC + kg) * HK + v];
        Mnt[((size_t)n * CC + kg) * CC + o] = a / ksum[n * CC + kg];
    }
}

// ---------------------------------------------------------------- kernel 3
__global__ __launch_bounds__(256) void k_out(
    const float* __restrict__ qsm, const float* __restrict__ Mnt,
    const float* __restrict__ br, float* __restrict__ out)
{
    const int tid = threadIdx.x;
    const int n = blockIdx.x >> 9;
    const int p = ((blockIdx.x & 511) << 8) + tid;
    const size_t base = (size_t)n * CC * NV + (size_t)p;
    const float* __restrict__ Mb = Mnt + n * CC * CC;

    float acc[CC];
#pragma unroll
    for (int o = 0; o < CC; ++o) acc[o] = br[o];

    for (int ch = 0; ch < 6; ++ch) {
        float qr[16];
#pragma unroll
        for (int u = 0; u < 16; ++u)
            qr[u] = qsm[base + (size_t)(ch * 16 + u) * NV];
#pragma unroll
        for (int u = 0; u < 16; ++u) {
            const float q = qr[u];
            const float* __restrict__ mrow = Mb + (ch * 16 + u) * CC;  // contiguous
#pragma unroll
            for (int o = 0; o < CC; ++o) acc[o] = fmaf(mrow[o], q, acc[o]);
        }
    }
#pragma unroll
    for (int o = 0; o < CC; ++o) out[base + (size_t)o * NV] = acc[o];
}

// ---------------------------------------------------------------- launch
extern "C" void kernel_launch(void* const* d_in, const int* in_sizes, int n_in,
                              void* d_out, int out_size, void* d_ws, size_t ws_size,
                              hipStream_t stream) {
    const float* x  = (const float*)d_in[0];
    const float* Wk = (const float*)d_in[1];
    const float* bk = (const float*)d_in[2];
    const float* Wq = (const float*)d_in[3];
    const float* bq = (const float*)d_in[4];
    const float* Wv = (const float*)d_in[5];
    const float* bv = (const float*)d_in[6];
    const float* Wr = (const float*)d_in[7];
    const float* br = (const float*)d_in[8];
    float* out = (float*)d_out;

    float* ws = (float*)d_ws;
    const size_t BIG = (size_t)NB * CC * NV;     // 25,165,824 floats
    float* qsm  = ws;                            // [2,96,NV]
    float* ctx  = ws + BIG;                      // [2,96,24] = 4608
    float* ksum = ctx + (size_t)NB * CC * HK;    // [2,96]    = 192
    float* Mnt  = ksum + (size_t)NB * CC;        // [2,96,96] = 18432
    float* Wqt  = Mnt + (size_t)NB * CC * CC;    // [4,96,24] = 9216
    float* Wkt  = Wqt + CC * CC;
    float* Wvt  = Wkt + CC * CC;

    // zero atomic accumulators (ctx+ksum contiguous)
    hipMemsetAsync(ctx, 0, ((size_t)NB * CC * HK + (size_t)NB * CC) * sizeof(float), stream);

    k_prep<<<dim3((CC * CC + 255) / 256), dim3(256), 0, stream>>>(Wq, Wk, Wv, Wqt, Wkt, Wvt);
    k_fused<<<dim3(NB * BPN), dim3(256), 0, stream>>>(x, Wqt, bq, Wkt, bk, Wvt, bv, qsm, ctx, ksum);
    k_combine<<<dim3(NB), dim3(256), 0, stream>>>(Wr, ctx, ksum, Mnt);
    k_out<<<dim3(NB * 512), dim3(256), 0, stream>>>(qsm, Mnt, br, out);
}